// Round 7
// baseline (122.562 us; speedup 1.0000x reference)
//
#include <hip/hip_runtime.h>
#include <hip/hip_fp16.h>

#define NPOS 26688

struct PairInfo {
  int iq, v, Hs, gH, gW, base, per;
  unsigned magicPer, magicW;
  int tOfs, tN, tCb;     // teacher compact: texel offset, #cols, col base
  int sN, sCb;           // student compact: #cols, col base (locals: 12,0)
  float tx1, tx2, ty1, ty2;
  float sx1, sx2, sy1, sy2;
};

// magic = ceil(2^32/d); error-term checked for all used ranges
__constant__ PairInfo g_pairs[6] = {
  {0,1,32,25,24,    0,600, 7158279u,178956971u,    0,2, 7, 22,5, -0.80f,0.70f,-0.500f,-0.475f,  -0.90f,0.60f,-0.60f,0.60f},
  {0,2,12,25,24, 4800,600, 7158279u,178956971u,  512,2,17, 12,0, -0.75f,0.75f, 0.100f, 0.125f,  -0.80f,0.80f,-0.80f,0.80f},
  {0,3,12,22,24, 9600,528, 8134408u,178956971u, 1024,2,12, 12,0, -0.60f,0.90f,-0.200f,-0.178f,  -0.70f,0.90f,-0.90f,0.70f},
  {1,0,32,22,24,13824,528, 8134408u,178956971u, 1536,2,20, 24,7, -0.70f,0.80f, 0.300f, 0.322f,  -0.85f,0.65f,-0.50f,0.90f},
  {1,2,12,24,22,18048,528, 8134408u,195225787u, 2048,3,13, 12,0, -0.90f,0.50f,-0.100f,-0.076f,  -0.60f,0.95f,-0.95f,0.60f},
  {1,3,12,24,23,22272,552, 7780739u,186737709u, 2816,3,18, 12,0, -0.50f,0.95f, 0.200f, 0.224f,  -0.90f,0.90f,-0.40f,0.95f},
};

// sampled-column tables. g_ux: x -> LDS staging slot (-1 = not sampled)
__constant__ int g_ux[2][32] = {
  {-1,-1,-1,-1,-1,-1,-1, 0, 1,-1,-1,-1, 2, 3,-1,-1,-1, 4, 5,-1,-1,-1,-1,-1,-1,-1,-1,-1,-1,-1,-1,-1},
  {-1,-1,-1,-1,-1,-1,-1,-1,-1,-1,-1,-1,-1, 0, 1, 2,-1,-1, 3, 4, 5, 6,-1,-1,-1,-1,-1,-1,-1,-1,-1,-1},
};
// compact-teacher write entries (x=-100 pads never match)
__constant__ int g_tentX[2][8] = {
  { 7, 8,12,13,17,18,-100,-100},
  {13,14,15,18,19,20,  20,  21},
};
__constant__ int g_tentO[2][8] = {
  {   0,   0,1024,1024, 512, 512,   0,   0},
  {2048,2048,2048,2816,2816,2816,1536,1536},
};
__constant__ int g_tentN[2][8] = {
  {2,2,2,2,2,2,2,2},
  {3,3,3,3,3,3,2,2},
};
__constant__ int g_tentC[2][8] = {
  {0,1,0,1,0,1,0,0},
  {0,1,2,0,1,2,0,1},
};
// probs-kernel texel decode tables
__constant__ int g_cumTex[6] = {0, 512, 1024, 1536, 2048, 2816};
__constant__ int g_tN[6]    = {2, 2, 2, 2, 3, 3};
__constant__ int g_tCb[6]   = {7, 17, 12, 20, 13, 18};

__device__ inline float get_invtemp(const int* __restrict__ ep) {
  int e = ep[0];
  e = e < 0 ? 0 : (e > 99 ? 99 : e);
  float temp = (e < 30) ? (0.04f + (float)e * (0.03f / 29.0f)) : 0.07f;
  return 1.0f / temp;
}

__device__ inline float sel4(const float4& v, int q) {
  return q == 0 ? v.x : q == 1 ? v.y : q == 2 ? v.z : v.w;
}

typedef _Float16 hv2 __attribute__((ext_vector_type(2)));
__device__ inline float fdot2f(__half2 a, __half2 b, float c) {
#if defined(__has_builtin)
#if __has_builtin(__builtin_amdgcn_fdot2)
  return __builtin_amdgcn_fdot2(*reinterpret_cast<hv2*>(&a),
                                *reinterpret_cast<hv2*>(&b), c, false);
#else
  float2 af = __half22float2(a), bf = __half22float2(b);
  return fmaf(af.x, bf.x, fmaf(af.y, bf.y, c));
#endif
#else
  float2 af = __half22float2(a), bf = __half22float2(b);
  return fmaf(af.x, bf.x, fmaf(af.y, bf.y, c));
#endif
}

// ============ phase1: stats[0,1024) | t12[1024,3072) | t32[3072,16384) ============
__global__ __launch_bounds__(256) void dino_phase1(
    const float* __restrict__ tg0, const float* __restrict__ tg1,
    const float* __restrict__ cen, const int* __restrict__ ep,
    float* __restrict__ part_m, float* __restrict__ part_s,
    __half* __restrict__ Tc,
    const float* __restrict__ sl0, const float* __restrict__ sl1,
    __half* __restrict__ Sl0, __half* __restrict__ Sl1,
    const float* __restrict__ sg0, const float* __restrict__ sg1,
    __half* __restrict__ Sg0, __half* __restrict__ Sg1) {
  __shared__ float smem[7424];          // 29696 B: ldsLg[7*1056] + cenl[32]
  int bid = blockIdx.x;
  int t = threadIdx.x;

  if (bid < 1024) {
    // ---------- streaming stats: (view,b,cg32), contiguous 128KB read ----------
    int cg = bid & 63;
    int b = (bid >> 6) & 7;
    int view = bid >> 9;                // [0,2)
    const float* __restrict__ src = view ? tg1 : tg0;
    float invtemp = get_invtemp(ep);
    float* cenl = smem + 7392;
    if (t < 32) cenl[t] = cen[cg * 32 + t];
    __syncthreads();

    int y = t >> 3, x0 = (t & 7) * 4;   // thread owns texels y*32 + x0..x0+3
    int y33 = y * 33;
    int s0 = g_ux[view][x0], s1 = g_ux[view][x0 + 1];
    int s2 = g_ux[view][x0 + 2], s3 = g_ux[view][x0 + 3];
    const float* base = src + ((size_t)(b * 2048 + cg * 32)) * 1024 + t * 4;

    float4 m4 = make_float4(-1e30f, -1e30f, -1e30f, -1e30f);
    float4 s4 = make_float4(0.f, 0.f, 0.f, 0.f);
#pragma unroll 4
    for (int c = 0; c < 32; ++c) {
      float4 v = *reinterpret_cast<const float4*>(base + (size_t)c * 1024);
      float cv = cenl[c];
      float4 lg;
      lg.x = (v.x - cv) * invtemp; lg.y = (v.y - cv) * invtemp;
      lg.z = (v.z - cv) * invtemp; lg.w = (v.w - cv) * invtemp;
      if (s0 >= 0) smem[s0 * 1056 + y33 + c] = lg.x;
      if (s1 >= 0) smem[s1 * 1056 + y33 + c] = lg.y;
      if (s2 >= 0) smem[s2 * 1056 + y33 + c] = lg.z;
      if (s3 >= 0) smem[s3 * 1056 + y33 + c] = lg.w;
      float mn;
      mn = fmaxf(m4.x, lg.x); s4.x = s4.x * __expf(m4.x - mn) + __expf(lg.x - mn); m4.x = mn;
      mn = fmaxf(m4.y, lg.y); s4.y = s4.y * __expf(m4.y - mn) + __expf(lg.y - mn); m4.y = mn;
      mn = fmaxf(m4.z, lg.z); s4.z = s4.z * __expf(m4.z - mn) + __expf(lg.z - mn); m4.z = mn;
      mn = fmaxf(m4.w, lg.w); s4.w = s4.w * __expf(m4.w - mn) + __expf(lg.w - mn); m4.w = mn;
    }
    size_t prow = ((size_t)((view * 8 + b) * 64 + cg)) * 1024 + t * 4;
    *reinterpret_cast<float4*>(part_m + prow) = m4;
    *reinterpret_cast<float4*>(part_s + prow) = s4;

    // compact dLogit writes: owner thread, own LDS data (no barrier needed)
#pragma unroll
    for (int e = 0; e < 8; ++e) {
      int ex = g_tentX[view][e];
      int d = ex - x0;
      if (d >= 0 && d < 4) {
        int slot = g_ux[view][ex];
        float mm = sel4(m4, d);
        int tex = g_tentO[view][e] + (b * 32 + y) * g_tentN[view][e] + g_tentC[view][e];
        tex = min(max(tex, 0), 3583);
        __half hv[32];
#pragma unroll
        for (int c = 0; c < 32; ++c)
          hv[c] = __float2half(smem[slot * 1056 + y33 + c] - mm);
        uint4* dst = reinterpret_cast<uint4*>(Tc + (size_t)tex * 2048 + cg * 32);
        const uint4* sv = reinterpret_cast<const uint4*>(hv);
        dst[0] = sv[0]; dst[1] = sv[1]; dst[2] = sv[2]; dst[3] = sv[3];
      }
    }
    return;
  }

  if (bid < 3072) {
    // ---------- student 12x12 transpose, 16 ch/block: 2048 = v(2)*b(8)*ct(128) ----------
    float* tile = smem;                 // 16*145 = 2320
    int lb = bid - 1024;
    int ct = lb & 127;
    int g = lb >> 7;
    int b = g & 7;
    int vv = g >> 3;
    const float* __restrict__ src = vv ? sl1 : sl0;
    __half* __restrict__ dst = vv ? Sl1 : Sl0;
    const float* sp = src + ((size_t)(b * 2048 + ct * 16)) * 144;
#pragma unroll
    for (int k = 0; k < 9; ++k) {       // 2304 contiguous floats in
      int idx = t + 256 * k;
      int c = idx / 144;
      int yx = idx - c * 144;
      tile[c * 145 + yx] = sp[idx] * 10.f;
    }
    __syncthreads();
    __half* dp = dst + ((size_t)(b * 144)) * 2048 + ct * 16;
#pragma unroll
    for (int k = 0; k < 2; ++k) {       // 288 float4 chunks out
      int u = t + 256 * k;
      if (u < 288) {
        int yx = u >> 1, q8 = (u & 1) * 8;
        __half hv[8];
#pragma unroll
        for (int j = 0; j < 8; ++j) hv[j] = __float2half(tile[(q8 + j) * 145 + yx]);
        *reinterpret_cast<float4*>(dp + (size_t)yx * 2048 + q8) =
            *reinterpret_cast<float4*>(hv);
      }
    }
    return;
  }

  // ---------- student-global windowed transpose: 13312 = which(2)*b(8)*y(26)*ct(32) ----------
  float* tile = smem;                   // 64*33 = 2112
  int lb = bid - 3072;
  int ct = lb & 31;
  int t2 = lb >> 5;                     // [0,416)
  int yi = t2 % 26;
  int g = t2 / 26;                      // [0,16)
  int y = yi + 1;                       // rows 1..26 only (sampled window)
  int b = g & 7;
  int which = g >> 3;
  const float* __restrict__ src = which ? sg1 : sg0;
  __half* __restrict__ dst = which ? Sg1 : Sg0;
  int cb = which ? 5 : 7;
  int n = which ? 22 : 24;

  int xg = t & 7, ch = t >> 3;
  const float* sp = src + (((size_t)(b * 2048 + ct * 64 + ch)) * 32 + y) * 32 + xg * 4;
  float4 v0 = *reinterpret_cast<const float4*>(sp);
  float4 v1 = *reinterpret_cast<const float4*>(sp + 32768);
  tile[ch * 33 + xg * 4 + 0] = v0.x * 10.f;
  tile[ch * 33 + xg * 4 + 1] = v0.y * 10.f;
  tile[ch * 33 + xg * 4 + 2] = v0.z * 10.f;
  tile[ch * 33 + xg * 4 + 3] = v0.w * 10.f;
  tile[(ch + 32) * 33 + xg * 4 + 0] = v1.x * 10.f;
  tile[(ch + 32) * 33 + xg * 4 + 1] = v1.y * 10.f;
  tile[(ch + 32) * 33 + xg * 4 + 2] = v1.z * 10.f;
  tile[(ch + 32) * 33 + xg * 4 + 3] = v1.w * 10.f;
  __syncthreads();
  int xx = t >> 3, ccq = (t & 7) * 8;
  if (xx >= cb && xx < cb + n) {
    __half hv[8];
#pragma unroll
    for (int j = 0; j < 8; ++j) hv[j] = __float2half(tile[(ccq + j) * 33 + xx]);
    __half* dp = dst + ((size_t)((b * 32 + y) * n + (xx - cb))) * 2048 + ct * 64 + ccq;
    *reinterpret_cast<float4*>(dp) = *reinterpret_cast<float4*>(hv);
  }
}

// ============ probs: Tc dlogits -> Tp probs, merging 64 group-partials ============
union H8 { uint4 u; __half2 h[4]; };

__global__ __launch_bounds__(256) void dino_probs(
    const __half* __restrict__ Tc, __half* __restrict__ Tp,
    const float* __restrict__ part_m, const float* __restrict__ part_s) {
  __shared__ float pr[66];              // [0,64): group maxes; 64: M; 65: 1/S
  int bid = blockIdx.x;                 // 3584 texels
  int t = threadIdx.x;
  int p = 0;
#pragma unroll
  for (int q = 1; q < 6; ++q) p += (bid >= g_cumTex[q]) ? 1 : 0;
  int r = bid - g_cumTex[p];
  int n = g_tN[p];
  int by = (n == 2) ? (r >> 1) : (r / 3);
  by = min(max(by, 0), 255);
  int ci = min(max(r - by * n, 0), n - 1);
  int x = g_tCb[p] + ci;                // <= 21 < 32
  int view = (p >= 3) ? 1 : 0;
  int b = by >> 5, y = by & 31;
  int vb = view * 8 + b;

  if (t < 64) {
    float mg = part_m[((size_t)(vb * 64 + t)) * 1024 + y * 32 + x];
    float sg = part_s[((size_t)(vb * 64 + t)) * 1024 + y * 32 + x];
    pr[t] = mg;
    float M = mg;
#pragma unroll
    for (int off = 32; off; off >>= 1) M = fmaxf(M, __shfl_xor(M, off));
    float sv = sg * __expf(mg - M);
#pragma unroll
    for (int off = 32; off; off >>= 1) sv += __shfl_xor(sv, off);
    if (t == 0) { pr[64] = M; pr[65] = 1.f / sv; }
  }
  __syncthreads();
  float off = pr[t >> 2] - pr[64];
  float invS = pr[65];

  int tex = min(g_cumTex[p] + by * n + ci, 3583);
  size_t base = (size_t)tex * 2048 + t * 8;
  H8 hh;
  hh.u = *reinterpret_cast<const uint4*>(Tc + base);
#pragma unroll
  for (int pc = 0; pc < 4; ++pc) {
    float2 f = __half22float2(hh.h[pc]);
    f.x = __expf(f.x + off) * invS;
    f.y = __expf(f.y + off) * invS;
    hh.h[pc] = __floats2half2_rn(f.x, f.y);
  }
  *reinterpret_cast<uint4*>(Tp + base) = hh.u;
}

// ============ main: 1 wave per position, compact layouts ============
__global__ __launch_bounds__(256) void dino_main(
    const __half* __restrict__ Tp,
    const __half* __restrict__ S0, const __half* __restrict__ S1,
    const __half* __restrict__ S2, const __half* __restrict__ S3,
    float* __restrict__ losses) {
  int wid = threadIdx.x >> 6, lane = threadIdx.x & 63;
  int pair = blockIdx.x / 1200;
  int slot = blockIdx.x - pair * 1200;
  PairInfo pi = g_pairs[pair];
  int posInPair = slot * 4 + wid;
  if (posInPair >= pi.per * 8) return;

  unsigned up = (unsigned)posInPair;
  int b = (int)__umulhi(up, pi.magicPer);
  b = min(max(b, 0), 7);
  int r = posInPair - b * pi.per;
  r = min(max(r, 0), pi.per - 1);
  int i = (int)__umulhi((unsigned)r, pi.magicW);
  i = min(max(i, 0), pi.gH - 1);
  int j = r - i * pi.gW;
  j = min(max(j, 0), pi.gW - 1);

  // reference swaps gx/gy: image COLUMN from y-linspace (i), ROW from x-linspace (j)
  float tyy = pi.ty1 + (float)i * (pi.ty2 - pi.ty1) / (float)(pi.gH - 1);
  float txx = pi.tx1 + (float)j * (pi.tx2 - pi.tx1) / (float)(pi.gW - 1);
  float tix = fminf(fmaxf((tyy + 1.0f) * 16.0f - 0.5f, 0.0f), 31.0f);
  float tiy = fminf(fmaxf((txx + 1.0f) * 16.0f - 0.5f, 0.0f), 31.0f);
  int tx0 = (int)tix, ty0 = (int)tiy;
  float wxt = tix - (float)tx0, wyt = tiy - (float)ty0;
  int tx1i = min(tx0 + 1, 31), ty1i = min(ty0 + 1, 31);

  int hs = pi.Hs;
  float hh = 0.5f * (float)hs, hm = (float)(hs - 1);
  float syy = pi.sy1 + (float)i * (pi.sy2 - pi.sy1) / (float)(pi.gH - 1);
  float sxx = pi.sx1 + (float)j * (pi.sx2 - pi.sx1) / (float)(pi.gW - 1);
  float six = fminf(fmaxf((syy + 1.0f) * hh - 0.5f, 0.0f), hm);
  float siy = fminf(fmaxf((sxx + 1.0f) * hh - 0.5f, 0.0f), hm);
  int sx0 = (int)six, sy0 = (int)siy;
  float wxs = six - (float)sx0, wys = siy - (float)sy0;
  int sx1i = min(sx0 + 1, hs - 1), sy1i = min(sy0 + 1, hs - 1);

  const __half* __restrict__ S =
      (pi.v == 0) ? S0 : (pi.v == 1) ? S1 : (pi.v == 2) ? S2 : S3;

  int tc0 = min(max(tx0 - pi.tCb, 0), pi.tN - 1);
  int tc1 = min(max(tx1i - pi.tCb, 0), pi.tN - 1);
  int trow = pi.tOfs + (b * 32 + ty0) * pi.tN;
  int trow1 = pi.tOfs + (b * 32 + ty1i) * pi.tN;
  int toff00 = min(trow + tc0, 3583) * 2048;
  int toff01 = min(trow + tc1, 3583) * 2048;
  int toff10 = min(trow1 + tc0, 3583) * 2048;
  int toff11 = min(trow1 + tc1, 3583) * 2048;
  int sc0 = min(max(sx0 - pi.sCb, 0), pi.sN - 1);
  int sc1 = min(max(sx1i - pi.sCb, 0), pi.sN - 1);
  int soff00 = ((b * hs + sy0) * pi.sN + sc0) * 2048;
  int soff01 = ((b * hs + sy0) * pi.sN + sc1) * 2048;
  int soff10 = ((b * hs + sy1i) * pi.sN + sc0) * 2048;
  int soff11 = ((b * hs + sy1i) * pi.sN + sc1) * 2048;

  __half2 wt00 = __float2half2_rn((1.f - wyt) * (1.f - wxt));
  __half2 wt01 = __float2half2_rn((1.f - wyt) * wxt);
  __half2 wt10 = __float2half2_rn(wyt * (1.f - wxt));
  __half2 wt11 = __float2half2_rn(wyt * wxt);
  __half2 ws00 = __float2half2_rn((1.f - wys) * (1.f - wxs));
  __half2 ws01 = __float2half2_rn((1.f - wys) * wxs);
  __half2 ws10 = __float2half2_rn(wys * (1.f - wxs));
  __half2 ws11 = __float2half2_rn(wys * wxs);

  float sum = 0.f, dot = 0.f;
#pragma unroll
  for (int k = 0; k < 4; ++k) {
    int c0 = (k << 9) + (lane << 3);
    H8 t00, t01, t10, t11, a00, a01, a10, a11;
    t00.u = *reinterpret_cast<const uint4*>(Tp + toff00 + c0);
    t01.u = *reinterpret_cast<const uint4*>(Tp + toff01 + c0);
    t10.u = *reinterpret_cast<const uint4*>(Tp + toff10 + c0);
    t11.u = *reinterpret_cast<const uint4*>(Tp + toff11 + c0);
    a00.u = *reinterpret_cast<const uint4*>(S + soff00 + c0);
    a01.u = *reinterpret_cast<const uint4*>(S + soff01 + c0);
    a10.u = *reinterpret_cast<const uint4*>(S + soff10 + c0);
    a11.u = *reinterpret_cast<const uint4*>(S + soff11 + c0);
#pragma unroll
    for (int p = 0; p < 4; ++p) {
      __half2 tc2 = __hmul2(wt00, t00.h[p]);
      tc2 = __hfma2(wt01, t01.h[p], tc2);
      tc2 = __hfma2(wt10, t10.h[p], tc2);
      tc2 = __hfma2(wt11, t11.h[p], tc2);
      __half2 sc2 = __hmul2(ws00, a00.h[p]);
      sc2 = __hfma2(ws01, a01.h[p], sc2);
      sc2 = __hfma2(ws10, a10.h[p], sc2);
      sc2 = __hfma2(ws11, a11.h[p], sc2);
      dot = fdot2f(tc2, sc2, dot);
      float2 scf = __half22float2(sc2);
      sum += __expf(scf.x);
      sum += __expf(scf.y);
    }
  }
#pragma unroll
  for (int off = 32; off; off >>= 1) {
    sum += __shfl_down(sum, off);
    dot += __shfl_down(dot, off);
  }
  if (lane == 0) losses[pi.base + posInPair] = logf(sum) - dot;
}

// ============ final mean ============
__global__ __launch_bounds__(1024) void dino_reduce(const float* __restrict__ losses,
                                                    float* __restrict__ out) {
  __shared__ double sd[1024];
  int t = threadIdx.x;
  double a = 0.0;
  for (int i4 = t; i4 < 6672; i4 += 1024) {
    float4 v = *reinterpret_cast<const float4*>(losses + i4 * 4);
    a += (double)v.x + (double)v.y + (double)v.z + (double)v.w;
  }
  sd[t] = a;
  __syncthreads();
  for (int off = 512; off; off >>= 1) {
    if (t < off) sd[t] += sd[t + off];
    __syncthreads();
  }
  if (t == 0) out[0] = (float)(sd[0] / (double)NPOS);
}

extern "C" void kernel_launch(void* const* d_in, const int* in_sizes, int n_in,
                              void* d_out, int out_size, void* d_ws, size_t ws_size,
                              hipStream_t stream) {
  const float* sg0 = (const float*)d_in[0];
  const float* sg1 = (const float*)d_in[1];
  const float* sl0 = (const float*)d_in[2];
  const float* sl1 = (const float*)d_in[3];
  const float* tg0 = (const float*)d_in[4];
  const float* tg1 = (const float*)d_in[5];
  const float* cen = (const float*)d_in[6];
  const int* epoch = (const int*)d_in[7];
  float* out = (float*)d_out;
  char* w = (char*)d_ws;

  // ws layout (bytes), total 95,682,560 (>=143.9 MB proven available in round 1)
  const size_t OFF_LOSS= 131072;       // 106752 (pad to 262144)
  const size_t OFF_PM  = 262144;       // 4 MB  (16 vb x 64 cg x 1024 texels f32)
  const size_t OFF_PS  = 4456448;      // 4 MB
  const size_t OFF_TC  = 8650752;      // 14,680,064 (3584 x 2048 fp16 dlogits)
  const size_t OFF_TP  = 23330816;     // 14,680,064 (3584 x 2048 fp16 probs)
  const size_t OFF_SG0 = 38010880;     // 25,165,824 (8*32*24*2048 fp16)
  const size_t OFF_SG1 = 63176704;     // 23,068,672 (8*32*22*2048 fp16)
  const size_t OFF_SL0 = 86245376;     // 4,718,592
  const size_t OFF_SL1 = 90963968;     // 4,718,592

  float* losses = (float*)(w + OFF_LOSS);
  float* part_m = (float*)(w + OFF_PM);
  float* part_s = (float*)(w + OFF_PS);
  __half* Tc  = (__half*)(w + OFF_TC);
  __half* Tp  = (__half*)(w + OFF_TP);
  __half* Sg0 = (__half*)(w + OFF_SG0);
  __half* Sg1 = (__half*)(w + OFF_SG1);
  __half* Sl0 = (__half*)(w + OFF_SL0);
  __half* Sl1 = (__half*)(w + OFF_SL1);

  // phase1 grid: stats[0,1024) | t12[1024,3072) | t32[3072,16384)
  dino_phase1<<<16384, 256, 0, stream>>>(tg0, tg1, cen, epoch, part_m, part_s, Tc,
                                         sl0, sl1, Sl0, Sl1, sg0, sg1, Sg0, Sg1);
  dino_probs<<<3584, 256, 0, stream>>>(Tc, Tp, part_m, part_s);
  dino_main<<<7200, 256, 0, stream>>>(Tp, Sg0, Sg1, Sl0, Sl1, losses);
  dino_reduce<<<1, 1024, 0, stream>>>(losses, out);
}